// Round 7
// baseline (429.733 us; speedup 1.0000x reference)
//
#include <hip/hip_runtime.h>
#include <hip/hip_fp16.h>

#define N_FEAT0 128
#define HID 64
#define NCLS 40

#define BSH 9            // log2 nodes per bucket
#define BSZ 512          // nodes per bucket
#define BCAP 12288       // slab capacity per bucket (mean 8192, sigma ~90 -> 45 sigma margin)
#define STILE 16384      // edges per scatter block

// ---------------- phase 1: LDS-binned scatter of edges into per-bucket slabs ----
// Record = (d & 511) << 17 | s   (s < 2^17 since N = 100000 < 131072).
__global__ __launch_bounds__(256) void scatter_kernel(const int* __restrict__ esrc,
                                                      const int* __restrict__ edst,
                                                      int* __restrict__ bfill,
                                                      int* __restrict__ slab, int E) {
  __shared__ int cnt[256];
  __shared__ int base[256];
  int t = threadIdx.x;
  int t0 = blockIdx.x * STILE;
  cnt[t] = 0;
  __syncthreads();

  // pass A: histogram
#pragma unroll 4
  for (int i = 0; i < STILE / 1024; ++i) {
    int e = t0 + i * 1024 + t * 4;
    if (e < E) {
      int4 d4 = *(const int4*)(edst + e);
      atomicAdd(&cnt[d4.x >> BSH], 1);
      atomicAdd(&cnt[d4.y >> BSH], 1);
      atomicAdd(&cnt[d4.z >> BSH], 1);
      atomicAdd(&cnt[d4.w >> BSH], 1);
    }
  }
  __syncthreads();
  int c = cnt[t];
  if (c > 0) base[t] = t * BCAP + atomicAdd(&bfill[t], c);
  cnt[t] = 0;
  __syncthreads();

  // pass B: binned write (tile is L2-warm from pass A)
#pragma unroll 4
  for (int i = 0; i < STILE / 1024; ++i) {
    int e = t0 + i * 1024 + t * 4;
    if (e < E) {
      int4 s4 = *(const int4*)(esrc + e);
      int4 d4 = *(const int4*)(edst + e);
#define EMIT(dd, ss)                                             \
      {                                                          \
        int b_ = (dd) >> BSH;                                    \
        int r_ = atomicAdd(&cnt[b_], 1);                         \
        slab[base[b_] + r_] = (((dd) & (BSZ - 1)) << 17) | (ss); \
      }
      EMIT(d4.x, s4.x)
      EMIT(d4.y, s4.y)
      EMIT(d4.z, s4.z)
      EMIT(d4.w, s4.w)
#undef EMIT
    }
  }
}

// ---------------- phase 2: per-bucket CSR finalize (bscan merged in) ----------
__global__ __launch_bounds__(256) void build_kernel(const int* __restrict__ slab,
                                                    const int* __restrict__ bfill,
                                                    int* __restrict__ row_ptr,
                                                    float* __restrict__ dinv,
                                                    int* __restrict__ ew,
                                                    int N, int nbuck) {
  __shared__ int cnt[512];
  __shared__ int pre[512];
  __shared__ int s2[256];
  int b = blockIdx.x;
  int t = threadIdx.x;
  int nbase = b << BSH;
  int nNodes = N - nbase;
  if (nNodes > BSZ) nNodes = BSZ;

  // ---- in-block inclusive scan of bucket sizes -> obase ----
  s2[t] = (t < nbuck) ? bfill[t] : 0;
  __syncthreads();
  for (int off = 1; off < 256; off <<= 1) {
    int u = (t >= off) ? s2[t - off] : 0;
    __syncthreads();
    s2[t] += u;
    __syncthreads();
  }
  int sz = bfill[b];
  int obase = s2[b] - sz;           // exclusive prefix for this bucket
  if (b == 0 && t == 255) row_ptr[N] = s2[255];  // total == E
  __syncthreads();

  cnt[t] = 0;
  cnt[t + 256] = 0;
  __syncthreads();

  int sbeg = b * BCAP;

  // per-node histogram
  for (int r = t; r < sz; r += 256) atomicAdd(&cnt[((unsigned)slab[sbeg + r]) >> 17], 1);
  __syncthreads();

  // exclusive prefix over 512 counters (pair-sum + 256-wide scan)
  int a = cnt[2 * t], c = cnt[2 * t + 1];
  s2[t] = a + c;
  __syncthreads();
  for (int off = 1; off < 256; off <<= 1) {
    int u = (t >= off) ? s2[t - off] : 0;
    __syncthreads();
    s2[t] += u;
    __syncthreads();
  }
  int ex = s2[t] - (a + c);
  pre[2 * t] = ex;
  pre[2 * t + 1] = ex + a;
  __syncthreads();

  // row_ptr + dinv (coalesced)
  if (t < nNodes) {
    row_ptr[nbase + t] = obase + pre[t];
    dinv[nbase + t] = rsqrtf((float)(cnt[t] + 1));
  }
  int t2 = t + 256;
  if (t2 < nNodes) {
    row_ptr[nbase + t2] = obase + pre[t2];
    dinv[nbase + t2] = rsqrtf((float)(cnt[t2] + 1));
  }
  __syncthreads();
  cnt[t] = 0;
  cnt[t + 256] = 0;
  __syncthreads();

  // final permute: slab (coalesced read, L2-warm) -> node-ordered ew
  for (int r = t; r < sz; r += 256) {
    int rec = slab[sbeg + r];
    int dloc = ((unsigned)rec) >> 17;
    int rank = atomicAdd(&cnt[dloc], 1);
    ew[obase + pre[dloc] + rank] = rec & 0x1FFFF;
  }
}

// ---------------- layer-0 dense GEMM (f32 in, fp16 PLANAR out) ---------------
// Out planar: Gp[plane][v][8 halves], plane = col/8. Planar layout makes each
// 8-feature slice a contiguous 1.6MB region -> XCD-L2-resident in aggs_kernel.
template <int K, int NC>
__global__ __launch_bounds__(256) void gemm_kernel(const float* __restrict__ A,
                                                   const float* __restrict__ W,
                                                   __half* __restrict__ Out,
                                                   const float* __restrict__ rowscale,
                                                   int N) {
  constexpr int BK = 64;
  constexpr int LDSS = 68;
  __shared__ float As[128 * LDSS];

  int t = threadIdx.x;
  int lane = t & 63;
  int wave = t >> 6;
  int c4 = lane & 15;
  int qr = lane >> 4;
  int r0 = blockIdx.x * 128;

  int wc = 4 * c4;                   // NC=64: all in-bounds

  float4 acc[8];
#pragma unroll
  for (int m = 0; m < 8; ++m) acc[m] = make_float4(0.f, 0.f, 0.f, 0.f);

  for (int kc = 0; kc < K; kc += BK) {
    __syncthreads();
#pragma unroll
    for (int i = 0; i < 8; ++i) {
      int idx = t + i * 256;
      int row = idx >> 4;
      int cq = idx & 15;
      int gr = r0 + row;
      if (gr >= N) gr = N - 1;
      float4 v = *(const float4*)(A + (size_t)gr * K + kc + 4 * cq);
      *(float4*)(As + row * LDSS + 4 * cq) = v;
    }
    __syncthreads();

#pragma unroll 2
    for (int kk = 0; kk < BK / 4; ++kk) {
      float4 w[4];
#pragma unroll
      for (int k = 0; k < 4; ++k)
        w[k] = *(const float4*)(W + (size_t)(kc + kk * 4 + k) * NC + wc);
#pragma unroll
      for (int m = 0; m < 8; ++m) {
        int lrow = wave * 32 + qr + 4 * m;
        float4 a = *(const float4*)(As + lrow * LDSS + kk * 4);
        acc[m].x = fmaf(a.x, w[0].x, acc[m].x);
        acc[m].y = fmaf(a.x, w[0].y, acc[m].y);
        acc[m].z = fmaf(a.x, w[0].z, acc[m].z);
        acc[m].w = fmaf(a.x, w[0].w, acc[m].w);
        acc[m].x = fmaf(a.y, w[1].x, acc[m].x);
        acc[m].y = fmaf(a.y, w[1].y, acc[m].y);
        acc[m].z = fmaf(a.y, w[1].z, acc[m].z);
        acc[m].w = fmaf(a.y, w[1].w, acc[m].w);
        acc[m].x = fmaf(a.z, w[2].x, acc[m].x);
        acc[m].y = fmaf(a.z, w[2].y, acc[m].y);
        acc[m].z = fmaf(a.z, w[2].z, acc[m].z);
        acc[m].w = fmaf(a.z, w[2].w, acc[m].w);
        acc[m].x = fmaf(a.w, w[3].x, acc[m].x);
        acc[m].y = fmaf(a.w, w[3].y, acc[m].y);
        acc[m].z = fmaf(a.w, w[3].z, acc[m].z);
        acc[m].w = fmaf(a.w, w[3].w, acc[m].w);
      }
    }
  }

  {
    int plane = c4 >> 1;             // col/8
    int hoff = (c4 & 1) * 4;         // half-offset within slice
#pragma unroll
    for (int m = 0; m < 8; ++m) {
      int gr = r0 + wave * 32 + qr + 4 * m;
      if (gr < N) {
        float ds = rowscale[gr];
        union { __half2 h[2]; uint2 u; } cv;
        cv.h[0] = __floats2half2_rn(ds * acc[m].x, ds * acc[m].y);
        cv.h[1] = __floats2half2_rn(ds * acc[m].z, ds * acc[m].w);
        *(uint2*)(Out + (size_t)plane * N * 8 + (size_t)gr * 8 + hoff) = cv.u;
      }
    }
  }
}

// ---------------- hidden-layer GEMM: fp16 A (K=64), f32 W, fp16 out ----------
// PLANAR=true -> plane-major output (for aggs_kernel); false -> row-major.
template <int NC, bool PLANAR>
__global__ __launch_bounds__(256) void gemm_h_kernel(const __half* __restrict__ A,
                                                     const float* __restrict__ W,
                                                     __half* __restrict__ Out,
                                                     const float* __restrict__ rowscale,
                                                     int N) {
  constexpr int K = 64;
  constexpr int LDSH = 76;
  __shared__ __half As[128 * LDSH];

  int t = threadIdx.x;
  int lane = t & 63;
  int wave = t >> 6;
  int c4 = lane & 15;
  int qr = lane >> 4;
  int r0 = blockIdx.x * 128;

  int wc = 4 * c4;
  if (wc > NC - 4) wc = NC - 4;
  bool cok = (wc == 4 * c4);

  float4 acc[8];
#pragma unroll
  for (int m = 0; m < 8; ++m) acc[m] = make_float4(0.f, 0.f, 0.f, 0.f);

#pragma unroll
  for (int i = 0; i < 4; ++i) {
    int idx = t + i * 256;
    int row = idx >> 3;
    int cq = idx & 7;
    int gr = r0 + row;
    if (gr >= N) gr = N - 1;
    uint4 v = *(const uint4*)(A + (size_t)gr * K + cq * 8);
    *(uint4*)(As + row * LDSH + cq * 8) = v;
  }
  __syncthreads();

#pragma unroll 2
  for (int kk = 0; kk < 8; ++kk) {
    float4 w[8];
#pragma unroll
    for (int k = 0; k < 8; ++k)
      w[k] = *(const float4*)(W + (size_t)(kk * 8 + k) * NC + wc);
#pragma unroll
    for (int m = 0; m < 8; ++m) {
      int lrow = wave * 32 + qr + 4 * m;
      uint4 av = *(const uint4*)(As + lrow * LDSH + kk * 8);
      const __half2* h2 = (const __half2*)&av;
      float2 f0 = __half22float2(h2[0]);
      float2 f1 = __half22float2(h2[1]);
      float2 f2 = __half22float2(h2[2]);
      float2 f3 = __half22float2(h2[3]);
#define FMA4(aa, ww)                              \
      acc[m].x = fmaf(aa, ww.x, acc[m].x);        \
      acc[m].y = fmaf(aa, ww.y, acc[m].y);        \
      acc[m].z = fmaf(aa, ww.z, acc[m].z);        \
      acc[m].w = fmaf(aa, ww.w, acc[m].w);
      FMA4(f0.x, w[0]) FMA4(f0.y, w[1])
      FMA4(f1.x, w[2]) FMA4(f1.y, w[3])
      FMA4(f2.x, w[4]) FMA4(f2.y, w[5])
      FMA4(f3.x, w[6]) FMA4(f3.y, w[7])
#undef FMA4
    }
  }

  if (cok) {
#pragma unroll
    for (int m = 0; m < 8; ++m) {
      int gr = r0 + wave * 32 + qr + 4 * m;
      if (gr < N) {
        float ds = rowscale[gr];
        union { __half2 h[2]; uint2 u; } cv;
        cv.h[0] = __floats2half2_rn(ds * acc[m].x, ds * acc[m].y);
        cv.h[1] = __floats2half2_rn(ds * acc[m].z, ds * acc[m].w);
        if constexpr (PLANAR) {
          int plane = c4 >> 1;
          int hoff = (c4 & 1) * 4;
          *(uint2*)(Out + (size_t)plane * N * 8 + (size_t)gr * 8 + hoff) = cv.u;
        } else {
          *(uint2*)(Out + (size_t)gr * NC + wc) = cv.u;
        }
      }
    }
  }
}

// ---------------- feature-split aggregation (F=64, planar G) ----------------
// Slice fo = blockIdx & 7 -> blocks of one residue land on one XCD (round-robin
// dispatch); grid 2048 = 8 blk/CU x 256 CU -> ALL blocks resident at t=0, so
// the assignment is static. Each XCD's gather working set = one contiguous
// 1.6MB plane -> L2-resident; the L3/fabric wall (48.5us pinned) disappears.
// Wave = 4 node-groups x 16 edge-lanes; lane gathers one 16B slice-row.
__global__ __launch_bounds__(256) void aggs_kernel(const __half* __restrict__ Gp,
                                                   const int* __restrict__ row_ptr,
                                                   const int* __restrict__ ew,
                                                   const float* __restrict__ dinv,
                                                   __half* __restrict__ Hout, int N) {
  int fo = blockIdx.x & 7;
  int chunk = blockIdx.x >> 3;
  int nch = gridDim.x >> 3;
  int lane = threadIdx.x & 63;
  int wv = threadIdx.x >> 6;         // wave 0..3
  int grp = lane >> 4;               // node group 0..3
  int lig = lane & 15;               // edge lane 0..15
  const __half* g = Gp + (size_t)fo * N * 8;

  int per = (N + nch - 1) / nch;
  int v0 = chunk * per;
  int v1 = v0 + per;
  if (v1 > N) v1 = N;

  for (int v = v0 + wv * 4 + grp; v < v1; v += 16) {
    float acc[8];
#pragma unroll
    for (int i = 0; i < 8; ++i) acc[i] = 0.f;

#define GLD(s) (*(const uint4*)(g + (size_t)(s) * 8))
    auto addrow = [&](uint4 q) {
      const __half2* h2 = (const __half2*)&q;
#pragma unroll
      for (int i = 0; i < 4; ++i) {
        float2 f2 = __half22float2(h2[i]);
        acc[2 * i] += f2.x;
        acc[2 * i + 1] += f2.y;
      }
    };

    int beg = row_ptr[v];
    int end = row_ptr[v + 1];
    if (lig == 0) addrow(GLD(v));    // self-loop term
    for (int j = beg + lig; j < end; j += 16) addrow(GLD(ew[j]));
#undef GLD

    // fold the 16 edge-lanes (masks 1,2,4,8 stay within the group)
#pragma unroll
    for (int m = 1; m <= 8; m <<= 1)
#pragma unroll
      for (int i = 0; i < 8; ++i) acc[i] += __shfl_xor(acc[i], m);

    if (lig == 0) {
      float dv = dinv[v];
      union { __half2 h2[4]; uint4 u; } cv;
      cv.h2[0] = __floats2half2_rn(fmaxf(dv * acc[0], 0.f), fmaxf(dv * acc[1], 0.f));
      cv.h2[1] = __floats2half2_rn(fmaxf(dv * acc[2], 0.f), fmaxf(dv * acc[3], 0.f));
      cv.h2[2] = __floats2half2_rn(fmaxf(dv * acc[4], 0.f), fmaxf(dv * acc[5], 0.f));
      cv.h2[3] = __floats2half2_rn(fmaxf(dv * acc[6], 0.f), fmaxf(dv * acc[7], 0.f));
      *(uint4*)(Hout + (size_t)v * HID + fo * 8) = cv.u;
    }
  }
}

// ---------------- final sparse aggregation (F=40 row-major, f32 out) ---------
template <int F>
__global__ __launch_bounds__(256) void agg_kernel(const __half* __restrict__ G,
                                                  const int* __restrict__ row_ptr,
                                                  const int* __restrict__ ew,
                                                  const float* __restrict__ dinv,
                                                  float* __restrict__ Hout, int N) {
  constexpr int FO = F / 8;
  int gid = blockIdx.x * blockDim.x + threadIdx.x;
  int v = gid >> 6;
  if (v >= N) return;
  int lane = threadIdx.x & 63;
  int eg = lane >> 3;
  int fo = lane & 7;
  bool fok = (fo < FO);
  int foc = fok ? fo : FO - 1;

  float acc[8];
#pragma unroll
  for (int i = 0; i < 8; ++i) acc[i] = 0.f;

#define GLD(s) (*(const uint4*)(G + (size_t)(s) * F + foc * 8))
  auto addrow = [&](uint4 q) {
    const __half2* h = (const __half2*)&q;
#pragma unroll
    for (int i = 0; i < 4; ++i) {
      float2 f = __half22float2(h[i]);
      acc[2 * i] += f.x;
      acc[2 * i + 1] += f.y;
    }
  };

  if (eg == 0) addrow(GLD(v));

  int beg = __builtin_amdgcn_readfirstlane(row_ptr[v]);
  int end = __builtin_amdgcn_readfirstlane(row_ptr[v + 1]);
  int j = beg;
  for (; j + 16 <= end; j += 16) {
    int s0 = ew[j + eg];
    int s1 = ew[j + 8 + eg];
    uint4 a = GLD(s0);
    uint4 b = GLD(s1);
    addrow(a);
    addrow(b);
  }
  if (j + 8 <= end) {
    addrow(GLD(ew[j + eg]));
    j += 8;
  }
  {
    int idx = j + eg;
    if (idx < end) addrow(GLD(ew[idx]));
  }
#undef GLD

#pragma unroll
  for (int m = 8; m <= 32; m <<= 1) {
#pragma unroll
    for (int i = 0; i < 8; ++i) acc[i] += __shfl_xor(acc[i], m);
  }

  if (fok) {
    float dv = dinv[v];
    float4 o0, o1;
    o0.x = fmaxf(dv * acc[0], 0.f);
    o0.y = fmaxf(dv * acc[1], 0.f);
    o0.z = fmaxf(dv * acc[2], 0.f);
    o0.w = fmaxf(dv * acc[3], 0.f);
    o1.x = fmaxf(dv * acc[4], 0.f);
    o1.y = fmaxf(dv * acc[5], 0.f);
    o1.z = fmaxf(dv * acc[6], 0.f);
    o1.w = fmaxf(dv * acc[7], 0.f);
    float4* outp = (float4*)(Hout + (size_t)v * F + fo * 8);
    outp[0] = o0;
    outp[1] = o1;
  }
}

extern "C" void kernel_launch(void* const* d_in, const int* in_sizes, int n_in,
                              void* d_out, int out_size, void* d_ws, size_t ws_size,
                              hipStream_t stream) {
  const float* x  = (const float*)d_in[0];
  const int*   eg = (const int*)d_in[1];
  const float* W0 = (const float*)d_in[2];
  const float* W1 = (const float*)d_in[3];
  const float* W2 = (const float*)d_in[4];
  float* out = (float*)d_out;

  const int N = in_sizes[0] / N_FEAT0;  // 100000
  const int E = in_sizes[1] / 2;        // 1600000
  const int* esrc = eg;
  const int* edst = eg + E;
  const int nbuck = (N + BSZ - 1) >> BSH;  // 196

  // workspace layout (256B aligned)
  char* p = (char*)d_ws;
  auto alloc = [&](size_t bytes) {
    char* r = p;
    p += (bytes + 255) & ~(size_t)255;
    return r;
  };
  int*    bfill   = (int*)alloc(256 * 4);
  int*    row_ptr = (int*)alloc((size_t)(N + 1) * 4);
  float*  dinv    = (float*)alloc((size_t)N * 4);
  int*    ew      = (int*)alloc((size_t)E * 4);
  __half* bufG    = (__half*)alloc((size_t)N * HID * 2);   // planar G (12.8 MB)
  __half* bufH    = (__half*)alloc((size_t)N * HID * 2);   // row-major H (12.8 MB)
  __half* bufG3   = (__half*)alloc((size_t)N * NCLS * 2);  // row-major G3 (8 MB)
  // slab aliases bufH (9.63 MB <= 12.8 MB); build reads it before aggs writes
  // bufH (stream-ordered).
  int* slab = (int*)bufH;

  hipMemsetAsync(bfill, 0, 256 * 4, stream);

  const int sblocks = (E + STILE - 1) / STILE;  // 98
  scatter_kernel<<<sblocks, 256, 0, stream>>>(esrc, edst, bfill, slab, E);
  build_kernel<<<nbuck, 256, 0, stream>>>(slab, bfill, row_ptr, dinv, ew, N, nbuck);

  const int gblocks = (N + 127) / 128;
  const int ablocks = (N + 3) / 4;
  const int sgrid = 8 * 256;  // 2048 blocks: 8/CU, all resident, residue->XCD static
  // layer 0: 128 -> 64 (dense, f32 in, planar fp16 out)
  gemm_kernel<128, 64><<<gblocks, 256, 0, stream>>>(x, W0, bufG, dinv, N);
  aggs_kernel<<<sgrid, 256, 0, stream>>>(bufG, row_ptr, ew, dinv, bufH, N);
  // layer 1: 64 -> 64 (fp16 in, planar fp16 out)
  gemm_h_kernel<64, true><<<gblocks, 256, 0, stream>>>(bufH, W1, bufG, dinv, N);
  aggs_kernel<<<sgrid, 256, 0, stream>>>(bufG, row_ptr, ew, dinv, bufH, N);
  // layer 2: 64 -> 40 (fp16 in, row-major fp16 out)
  gemm_h_kernel<40, false><<<gblocks, 256, 0, stream>>>(bufH, W2, bufG3, dinv, N);
  // final aggregation -> output (row-major)
  agg_kernel<40><<<ablocks, 256, 0, stream>>>(bufG3, row_ptr, ew, dinv, out, N);
}

// Round 9
// 334.571 us; speedup vs baseline: 1.2844x; 1.2844x over previous
//
#include <hip/hip_runtime.h>
#include <hip/hip_fp16.h>

#define N_FEAT0 128
#define HID 64
#define NCLS 40

#define BSH 9            // log2 nodes per bucket
#define BSZ 512          // nodes per bucket
#define BCAP 12288       // slab capacity per bucket (mean 8192, sigma ~90 -> 45 sigma margin)
#define STILE 4096       // edges per scatter block (391 blocks: round-8 occupancy fix)

// ---------------- phase 1: LDS-binned scatter of edges into per-bucket slabs ----
// Record = (d & 511) << 17 | s   (s < 2^17 since N = 100000 < 131072).
__global__ __launch_bounds__(256) void scatter_kernel(const int* __restrict__ esrc,
                                                      const int* __restrict__ edst,
                                                      int* __restrict__ bfill,
                                                      int* __restrict__ slab, int E) {
  __shared__ int cnt[256];
  __shared__ int base[256];
  int t = threadIdx.x;
  int t0 = blockIdx.x * STILE;
  cnt[t] = 0;
  __syncthreads();

  // pass A: histogram
#pragma unroll 4
  for (int i = 0; i < STILE / 1024; ++i) {
    int e = t0 + i * 1024 + t * 4;
    if (e < E) {
      int4 d4 = *(const int4*)(edst + e);
      atomicAdd(&cnt[d4.x >> BSH], 1);
      atomicAdd(&cnt[d4.y >> BSH], 1);
      atomicAdd(&cnt[d4.z >> BSH], 1);
      atomicAdd(&cnt[d4.w >> BSH], 1);
    }
  }
  __syncthreads();
  int c = cnt[t];
  if (c > 0) base[t] = t * BCAP + atomicAdd(&bfill[t], c);
  cnt[t] = 0;
  __syncthreads();

  // pass B: binned write (tile is L2-warm from pass A)
#pragma unroll 4
  for (int i = 0; i < STILE / 1024; ++i) {
    int e = t0 + i * 1024 + t * 4;
    if (e < E) {
      int4 s4 = *(const int4*)(esrc + e);
      int4 d4 = *(const int4*)(edst + e);
#define EMIT(dd, ss)                                             \
      {                                                          \
        int b_ = (dd) >> BSH;                                    \
        int r_ = atomicAdd(&cnt[b_], 1);                         \
        slab[base[b_] + r_] = (((dd) & (BSZ - 1)) << 17) | (ss); \
      }
      EMIT(d4.x, s4.x)
      EMIT(d4.y, s4.y)
      EMIT(d4.z, s4.z)
      EMIT(d4.w, s4.w)
#undef EMIT
    }
  }
}

// ---------------- phase 2: per-bucket CSR finalize (512 threads, bscan merged) --
// 512 threads: one native 512-wide scan over node counters (no pair-sum stage),
// permute loops stride 512, 2x waves/CU vs the 256-thread version.
__global__ __launch_bounds__(512) void build_kernel(const int* __restrict__ slab,
                                                    const int* __restrict__ bfill,
                                                    int* __restrict__ row_ptr,
                                                    float* __restrict__ dinv,
                                                    int* __restrict__ ew,
                                                    int N, int nbuck) {
  __shared__ int cnt[512];
  __shared__ int pre[512];
  __shared__ int sc[256];
  int b = blockIdx.x;
  int t = threadIdx.x;
  int nbase = b << BSH;
  int nNodes = N - nbase;
  if (nNodes > BSZ) nNodes = BSZ;

  // ---- in-block inclusive scan of bucket sizes (threads < 256) -> obase ----
  if (t < 256) sc[t] = (t < nbuck) ? bfill[t] : 0;
  __syncthreads();
  for (int off = 1; off < 256; off <<= 1) {
    int u = 0;
    if (t < 256 && t >= off) u = sc[t - off];
    __syncthreads();
    if (t < 256) sc[t] += u;
    __syncthreads();
  }
  int sz = bfill[b];
  int obase = sc[b] - sz;           // exclusive prefix for this bucket
  if (b == 0 && t == 0) row_ptr[N] = sc[255];  // total == E
  cnt[t] = 0;
  __syncthreads();

  int sbeg = b * BCAP;

  // per-node histogram
  for (int r = t; r < sz; r += 512) atomicAdd(&cnt[((unsigned)slab[sbeg + r]) >> 17], 1);
  __syncthreads();

  // exclusive prefix over 512 counters: direct 512-wide scan
  int c = cnt[t];
  pre[t] = c;
  __syncthreads();
  for (int off = 1; off < 512; off <<= 1) {
    int u = (t >= off) ? pre[t - off] : 0;
    __syncthreads();
    pre[t] += u;
    __syncthreads();
  }
  int ex = pre[t] - c;

  // row_ptr + dinv (coalesced, one node per thread)
  if (t < nNodes) {
    row_ptr[nbase + t] = obase + ex;
    dinv[nbase + t] = rsqrtf((float)(c + 1));
  }
  __syncthreads();
  pre[t] = ex;
  cnt[t] = 0;
  __syncthreads();

  // final permute: slab (coalesced read, L2-warm) -> node-ordered ew
  for (int r = t; r < sz; r += 512) {
    int rec = slab[sbeg + r];
    int dloc = ((unsigned)rec) >> 17;
    int rank = atomicAdd(&cnt[dloc], 1);
    ew[obase + pre[dloc] + rank] = rec & 0x1FFFF;
  }
}

// ---------------- layer-0 dense GEMM (f32 in, fp16 out, dinv epilogue) -------
template <int K, int NC>
__global__ __launch_bounds__(256) void gemm_kernel(const float* __restrict__ A,
                                                   const float* __restrict__ W,
                                                   __half* __restrict__ Out,
                                                   const float* __restrict__ rowscale,
                                                   int N) {
  constexpr int BK = 64;
  constexpr int LDSS = 68;
  __shared__ float As[128 * LDSS];

  int t = threadIdx.x;
  int lane = t & 63;
  int wave = t >> 6;
  int c4 = lane & 15;
  int qr = lane >> 4;
  int r0 = blockIdx.x * 128;

  int wc = 4 * c4;
  if (wc > NC - 4) wc = NC - 4;
  bool cok = (wc == 4 * c4);

  float4 acc[8];
#pragma unroll
  for (int m = 0; m < 8; ++m) acc[m] = make_float4(0.f, 0.f, 0.f, 0.f);

  for (int kc = 0; kc < K; kc += BK) {
    __syncthreads();
#pragma unroll
    for (int i = 0; i < 8; ++i) {
      int idx = t + i * 256;
      int row = idx >> 4;
      int cq = idx & 15;
      int gr = r0 + row;
      if (gr >= N) gr = N - 1;
      float4 v = *(const float4*)(A + (size_t)gr * K + kc + 4 * cq);
      *(float4*)(As + row * LDSS + 4 * cq) = v;
    }
    __syncthreads();

#pragma unroll 2
    for (int kk = 0; kk < BK / 4; ++kk) {
      float4 w[4];
#pragma unroll
      for (int k = 0; k < 4; ++k)
        w[k] = *(const float4*)(W + (size_t)(kc + kk * 4 + k) * NC + wc);
#pragma unroll
      for (int m = 0; m < 8; ++m) {
        int lrow = wave * 32 + qr + 4 * m;
        float4 a = *(const float4*)(As + lrow * LDSS + kk * 4);
        acc[m].x = fmaf(a.x, w[0].x, acc[m].x);
        acc[m].y = fmaf(a.x, w[0].y, acc[m].y);
        acc[m].z = fmaf(a.x, w[0].z, acc[m].z);
        acc[m].w = fmaf(a.x, w[0].w, acc[m].w);
        acc[m].x = fmaf(a.y, w[1].x, acc[m].x);
        acc[m].y = fmaf(a.y, w[1].y, acc[m].y);
        acc[m].z = fmaf(a.y, w[1].z, acc[m].z);
        acc[m].w = fmaf(a.y, w[1].w, acc[m].w);
        acc[m].x = fmaf(a.z, w[2].x, acc[m].x);
        acc[m].y = fmaf(a.z, w[2].y, acc[m].y);
        acc[m].z = fmaf(a.z, w[2].z, acc[m].z);
        acc[m].w = fmaf(a.z, w[2].w, acc[m].w);
        acc[m].x = fmaf(a.w, w[3].x, acc[m].x);
        acc[m].y = fmaf(a.w, w[3].y, acc[m].y);
        acc[m].z = fmaf(a.w, w[3].z, acc[m].z);
        acc[m].w = fmaf(a.w, w[3].w, acc[m].w);
      }
    }
  }

  if (cok) {
#pragma unroll
    for (int m = 0; m < 8; ++m) {
      int gr = r0 + wave * 32 + qr + 4 * m;
      if (gr < N) {
        float ds = rowscale[gr];
        union { __half2 h[2]; uint2 u; } cv;
        cv.h[0] = __floats2half2_rn(ds * acc[m].x, ds * acc[m].y);
        cv.h[1] = __floats2half2_rn(ds * acc[m].z, ds * acc[m].w);
        *(uint2*)(Out + (size_t)gr * NC + wc) = cv.u;
      }
    }
  }
}

// ---------------- hidden-layer GEMM: fp16 A (K=64), f32 W, fp16 out ----------
template <int NC>
__global__ __launch_bounds__(256) void gemm_h_kernel(const __half* __restrict__ A,
                                                     const float* __restrict__ W,
                                                     __half* __restrict__ Out,
                                                     const float* __restrict__ rowscale,
                                                     int N) {
  constexpr int K = 64;
  constexpr int LDSH = 76;
  __shared__ __half As[128 * LDSH];

  int t = threadIdx.x;
  int lane = t & 63;
  int wave = t >> 6;
  int c4 = lane & 15;
  int qr = lane >> 4;
  int r0 = blockIdx.x * 128;

  int wc = 4 * c4;
  if (wc > NC - 4) wc = NC - 4;
  bool cok = (wc == 4 * c4);

  float4 acc[8];
#pragma unroll
  for (int m = 0; m < 8; ++m) acc[m] = make_float4(0.f, 0.f, 0.f, 0.f);

#pragma unroll
  for (int i = 0; i < 4; ++i) {
    int idx = t + i * 256;
    int row = idx >> 3;
    int cq = idx & 7;
    int gr = r0 + row;
    if (gr >= N) gr = N - 1;
    uint4 v = *(const uint4*)(A + (size_t)gr * K + cq * 8);
    *(uint4*)(As + row * LDSH + cq * 8) = v;
  }
  __syncthreads();

#pragma unroll 2
  for (int kk = 0; kk < 8; ++kk) {
    float4 w[8];
#pragma unroll
    for (int k = 0; k < 8; ++k)
      w[k] = *(const float4*)(W + (size_t)(kk * 8 + k) * NC + wc);
#pragma unroll
    for (int m = 0; m < 8; ++m) {
      int lrow = wave * 32 + qr + 4 * m;
      uint4 av = *(const uint4*)(As + lrow * LDSH + kk * 8);
      const __half2* h2 = (const __half2*)&av;
      float2 f0 = __half22float2(h2[0]);
      float2 f1 = __half22float2(h2[1]);
      float2 f2 = __half22float2(h2[2]);
      float2 f3 = __half22float2(h2[3]);
#define FMA4(aa, ww)                              \
      acc[m].x = fmaf(aa, ww.x, acc[m].x);        \
      acc[m].y = fmaf(aa, ww.y, acc[m].y);        \
      acc[m].z = fmaf(aa, ww.z, acc[m].z);        \
      acc[m].w = fmaf(aa, ww.w, acc[m].w);
      FMA4(f0.x, w[0]) FMA4(f0.y, w[1])
      FMA4(f1.x, w[2]) FMA4(f1.y, w[3])
      FMA4(f2.x, w[4]) FMA4(f2.y, w[5])
      FMA4(f3.x, w[6]) FMA4(f3.y, w[7])
#undef FMA4
    }
  }

  if (cok) {
#pragma unroll
    for (int m = 0; m < 8; ++m) {
      int gr = r0 + wave * 32 + qr + 4 * m;
      if (gr < N) {
        float ds = rowscale[gr];
        union { __half2 h[2]; uint2 u; } cv;
        cv.h[0] = __floats2half2_rn(ds * acc[m].x, ds * acc[m].y);
        cv.h[1] = __floats2half2_rn(ds * acc[m].z, ds * acc[m].w);
        *(uint2*)(Out + (size_t)gr * NC + wc) = cv.u;
      }
    }
  }
}

// ---------------- sparse aggregation: one wave per node, fp16 gather ---------
// Row-major G: one edge = one 128B line request (line-rate optimal; round-7
// planar proved line-request count, not bytes, is the wall). 8 edge-slots x
// 8 feature-octs, f32 accumulate, 3-level shfl_xor fold.
template <int F, bool HOUT>
__global__ __launch_bounds__(256) void agg_kernel(const __half* __restrict__ G,
                                                  const int* __restrict__ row_ptr,
                                                  const int* __restrict__ ew,
                                                  const float* __restrict__ dinv,
                                                  void* __restrict__ HoutV, int N) {
  constexpr int FO = F / 8;
  int gid = blockIdx.x * blockDim.x + threadIdx.x;
  int v = gid >> 6;
  if (v >= N) return;
  int lane = threadIdx.x & 63;
  int eg = lane >> 3;
  int fo = lane & 7;
  bool fok = (fo < FO);
  int foc = fok ? fo : FO - 1;

  float acc[8];
#pragma unroll
  for (int i = 0; i < 8; ++i) acc[i] = 0.f;

#define GLD(s) (*(const uint4*)(G + (size_t)(s) * F + foc * 8))
  auto addrow = [&](uint4 q) {
    const __half2* h = (const __half2*)&q;
#pragma unroll
    for (int i = 0; i < 4; ++i) {
      float2 f = __half22float2(h[i]);
      acc[2 * i] += f.x;
      acc[2 * i + 1] += f.y;
    }
  };

  if (eg == 0) addrow(GLD(v));       // self-loop term

  int beg = __builtin_amdgcn_readfirstlane(row_ptr[v]);
  int end = __builtin_amdgcn_readfirstlane(row_ptr[v + 1]);
  int j = beg;
  for (; j + 16 <= end; j += 16) {
    int s0 = ew[j + eg];
    int s1 = ew[j + 8 + eg];
    uint4 a = GLD(s0);
    uint4 b = GLD(s1);
    addrow(a);
    addrow(b);
  }
  if (j + 8 <= end) {
    addrow(GLD(ew[j + eg]));
    j += 8;
  }
  {
    int idx = j + eg;
    if (idx < end) addrow(GLD(ew[idx]));
  }
#undef GLD

#pragma unroll
  for (int m = 8; m <= 32; m <<= 1) {
#pragma unroll
    for (int i = 0; i < 8; ++i) acc[i] += __shfl_xor(acc[i], m);
  }

  if (fok) {
    float dv = dinv[v];
    if constexpr (HOUT) {
      __half* Hout = (__half*)HoutV;
      union { __half2 h2[4]; uint4 u; } cv;
      cv.h2[0] = __floats2half2_rn(fmaxf(dv * acc[0], 0.f), fmaxf(dv * acc[1], 0.f));
      cv.h2[1] = __floats2half2_rn(fmaxf(dv * acc[2], 0.f), fmaxf(dv * acc[3], 0.f));
      cv.h2[2] = __floats2half2_rn(fmaxf(dv * acc[4], 0.f), fmaxf(dv * acc[5], 0.f));
      cv.h2[3] = __floats2half2_rn(fmaxf(dv * acc[6], 0.f), fmaxf(dv * acc[7], 0.f));
      *(uint4*)(Hout + (size_t)v * F + fo * 8) = cv.u;
    } else {
      float* Hout = (float*)HoutV;
      float4 o0, o1;
      o0.x = fmaxf(dv * acc[0], 0.f);
      o0.y = fmaxf(dv * acc[1], 0.f);
      o0.z = fmaxf(dv * acc[2], 0.f);
      o0.w = fmaxf(dv * acc[3], 0.f);
      o1.x = fmaxf(dv * acc[4], 0.f);
      o1.y = fmaxf(dv * acc[5], 0.f);
      o1.z = fmaxf(dv * acc[6], 0.f);
      o1.w = fmaxf(dv * acc[7], 0.f);
      float4* outp = (float4*)(Hout + (size_t)v * F + fo * 8);
      outp[0] = o0;
      outp[1] = o1;
    }
  }
}

extern "C" void kernel_launch(void* const* d_in, const int* in_sizes, int n_in,
                              void* d_out, int out_size, void* d_ws, size_t ws_size,
                              hipStream_t stream) {
  const float* x  = (const float*)d_in[0];
  const int*   eg = (const int*)d_in[1];
  const float* W0 = (const float*)d_in[2];
  const float* W1 = (const float*)d_in[3];
  const float* W2 = (const float*)d_in[4];
  float* out = (float*)d_out;

  const int N = in_sizes[0] / N_FEAT0;  // 100000
  const int E = in_sizes[1] / 2;        // 1600000
  const int* esrc = eg;
  const int* edst = eg + E;
  const int nbuck = (N + BSZ - 1) >> BSH;  // 196

  // workspace layout (256B aligned)
  char* p = (char*)d_ws;
  auto alloc = [&](size_t bytes) {
    char* r = p;
    p += (bytes + 255) & ~(size_t)255;
    return r;
  };
  int*    bfill   = (int*)alloc(256 * 4);
  int*    row_ptr = (int*)alloc((size_t)(N + 1) * 4);
  float*  dinv    = (float*)alloc((size_t)N * 4);
  int*    ew      = (int*)alloc((size_t)E * 4);
  __half* bufG    = (__half*)alloc((size_t)N * HID * 2);   // 12.8 MB (G1, then G2)
  __half* bufH    = (__half*)alloc((size_t)N * HID * 2);   // 12.8 MB (H1, then H2)
  __half* bufG3   = (__half*)alloc((size_t)N * NCLS * 2);  // 8 MB
  // slab aliases bufH (9.63 MB <= 12.8 MB); build reads it before agg1 writes
  // bufH (stream-ordered).
  int* slab = (int*)bufH;

  hipMemsetAsync(bfill, 0, 256 * 4, stream);

  const int sblocks = (E + STILE - 1) / STILE;  // 391
  scatter_kernel<<<sblocks, 256, 0, stream>>>(esrc, edst, bfill, slab, E);
  build_kernel<<<nbuck, 512, 0, stream>>>(slab, bfill, row_ptr, dinv, ew, N, nbuck);

  const int gblocks = (N + 127) / 128;
  const int ablocks = (N + 3) / 4;
  // layer 0: 128 -> 64 (dense, f32 in)
  gemm_kernel<128, 64><<<gblocks, 256, 0, stream>>>(x, W0, bufG, dinv, N);
  agg_kernel<64, true><<<ablocks, 256, 0, stream>>>(bufG, row_ptr, ew, dinv, bufH, N);
  // layer 1: 64 -> 64 (fp16 in)
  gemm_h_kernel<64><<<gblocks, 256, 0, stream>>>(bufH, W1, bufG, dinv, N);
  agg_kernel<64, true><<<ablocks, 256, 0, stream>>>(bufG, row_ptr, ew, dinv, bufH, N);
  // layer 2: 64 -> 40 (fp16 in)
  gemm_h_kernel<40><<<gblocks, 256, 0, stream>>>(bufH, W2, bufG3, dinv, N);
  agg_kernel<40, false><<<ablocks, 256, 0, stream>>>(bufG3, row_ptr, ew, dinv, out, N);
}

// Round 10
// 303.809 us; speedup vs baseline: 1.4145x; 1.1013x over previous
//
#include <hip/hip_runtime.h>
#include <hip/hip_fp16.h>

#define N_FEAT0 128
#define HID 64
#define NCLS 40

#define BSH 9            // log2 nodes per bucket
#define BSZ 512          // nodes per bucket
#define BCAP 12288       // slab capacity per bucket (mean 8192, sigma ~90 -> 45 sigma margin)
#define STILE 4096       // edges per scatter block (391 blocks)

typedef _Float16 half8 __attribute__((ext_vector_type(8)));
typedef float f32x4 __attribute__((ext_vector_type(4)));

// ---------------- phase 1: LDS-binned scatter of edges into per-bucket slabs ----
// Record = (d & 511) << 17 | s   (s < 2^17 since N = 100000 < 131072).
__global__ __launch_bounds__(256) void scatter_kernel(const int* __restrict__ esrc,
                                                      const int* __restrict__ edst,
                                                      int* __restrict__ bfill,
                                                      int* __restrict__ slab, int E) {
  __shared__ int cnt[256];
  __shared__ int base[256];
  int t = threadIdx.x;
  int t0 = blockIdx.x * STILE;
  cnt[t] = 0;
  __syncthreads();

  // pass A: histogram
#pragma unroll 4
  for (int i = 0; i < STILE / 1024; ++i) {
    int e = t0 + i * 1024 + t * 4;
    if (e < E) {
      int4 d4 = *(const int4*)(edst + e);
      atomicAdd(&cnt[d4.x >> BSH], 1);
      atomicAdd(&cnt[d4.y >> BSH], 1);
      atomicAdd(&cnt[d4.z >> BSH], 1);
      atomicAdd(&cnt[d4.w >> BSH], 1);
    }
  }
  __syncthreads();
  int c = cnt[t];
  if (c > 0) base[t] = t * BCAP + atomicAdd(&bfill[t], c);
  cnt[t] = 0;
  __syncthreads();

  // pass B: binned write (tile is L2-warm from pass A)
#pragma unroll 4
  for (int i = 0; i < STILE / 1024; ++i) {
    int e = t0 + i * 1024 + t * 4;
    if (e < E) {
      int4 s4 = *(const int4*)(esrc + e);
      int4 d4 = *(const int4*)(edst + e);
#define EMIT(dd, ss)                                             \
      {                                                          \
        int b_ = (dd) >> BSH;                                    \
        int r_ = atomicAdd(&cnt[b_], 1);                         \
        slab[base[b_] + r_] = (((dd) & (BSZ - 1)) << 17) | (ss); \
      }
      EMIT(d4.x, s4.x)
      EMIT(d4.y, s4.y)
      EMIT(d4.z, s4.z)
      EMIT(d4.w, s4.w)
#undef EMIT
    }
  }
}

// ---------------- phase 2: per-bucket CSR finalize (512 threads, bscan merged) --
__global__ __launch_bounds__(512) void build_kernel(const int* __restrict__ slab,
                                                    const int* __restrict__ bfill,
                                                    int* __restrict__ row_ptr,
                                                    float* __restrict__ dinv,
                                                    int* __restrict__ ew,
                                                    int N, int nbuck) {
  __shared__ int cnt[512];
  __shared__ int pre[512];
  __shared__ int sc[256];
  int b = blockIdx.x;
  int t = threadIdx.x;
  int nbase = b << BSH;
  int nNodes = N - nbase;
  if (nNodes > BSZ) nNodes = BSZ;

  // ---- in-block inclusive scan of bucket sizes (threads < 256) -> obase ----
  if (t < 256) sc[t] = (t < nbuck) ? bfill[t] : 0;
  __syncthreads();
  for (int off = 1; off < 256; off <<= 1) {
    int u = 0;
    if (t < 256 && t >= off) u = sc[t - off];
    __syncthreads();
    if (t < 256) sc[t] += u;
    __syncthreads();
  }
  int sz = bfill[b];
  int obase = sc[b] - sz;           // exclusive prefix for this bucket
  if (b == 0 && t == 0) row_ptr[N] = sc[255];  // total == E
  cnt[t] = 0;
  __syncthreads();

  int sbeg = b * BCAP;

  // per-node histogram
  for (int r = t; r < sz; r += 512) atomicAdd(&cnt[((unsigned)slab[sbeg + r]) >> 17], 1);
  __syncthreads();

  // exclusive prefix over 512 counters: direct 512-wide scan
  int c = cnt[t];
  pre[t] = c;
  __syncthreads();
  for (int off = 1; off < 512; off <<= 1) {
    int u = (t >= off) ? pre[t - off] : 0;
    __syncthreads();
    pre[t] += u;
    __syncthreads();
  }
  int ex = pre[t] - c;

  // row_ptr + dinv (coalesced, one node per thread)
  if (t < nNodes) {
    row_ptr[nbase + t] = obase + ex;
    dinv[nbase + t] = rsqrtf((float)(c + 1));
  }
  __syncthreads();
  pre[t] = ex;
  cnt[t] = 0;
  __syncthreads();

  // final permute: slab (coalesced read, L2-warm) -> node-ordered ew
  for (int r = t; r < sz; r += 512) {
    int rec = slab[sbeg + r];
    int dloc = ((unsigned)rec) >> 17;
    int rank = atomicAdd(&cnt[dloc], 1);
    ew[obase + pre[dloc] + rank] = rec & 0x1FFFF;
  }
}

// ---------------- W prep: transpose + fp16-convert the three weight matrices ----
// Wt0[64][128] = W0^T, Wt1[64][64] = W1^T, Wt2[48][64] = W2^T zero-padded to 48
// cols. Row-contiguous-in-k layout makes the MFMA B-fragment ONE 16B load.
__global__ __launch_bounds__(256) void prep_w_kernel(const float* __restrict__ W0,
                                                     const float* __restrict__ W1,
                                                     const float* __restrict__ W2,
                                                     __half* __restrict__ Wt0,
                                                     __half* __restrict__ Wt1,
                                                     __half* __restrict__ Wt2) {
  int id = blockIdx.x * 256 + threadIdx.x;
  if (id < 8192) {                       // Wt0: 64 x 128
    int c = id >> 7, k = id & 127;
    Wt0[id] = __float2half_rn(W0[k * 64 + c]);
  } else if (id < 8192 + 4096) {         // Wt1: 64 x 64
    int i = id - 8192;
    int c = i >> 6, k = i & 63;
    Wt1[i] = __float2half_rn(W1[k * 64 + c]);
  } else if (id < 8192 + 4096 + 3072) {  // Wt2: 48 x 64 (cols 40..47 zero)
    int i = id - 8192 - 4096;
    int c = i >> 6, k = i & 63;
    Wt2[i] = (c < NCLS) ? __float2half_rn(W2[k * NCLS + c]) : __half(0.f);
  }
}

// ---------------- MFMA GEMM: Out[r][c] = (half) dinv[r] * sum_k A[r][k] W[k][c] --
// v_mfma_f32_16x16x32_f16, verified layouts (guide m89/m91):
//   A-frag: row = lane&15, k = 8*(lane>>4)+i  -> one contiguous 16B load
//   B-frag: k = 8*(lane>>4)+i, col = lane&15  -> one 16B load from Wt[c][k]
//   D:      col = lane&15, row = 4*(lane>>4)+reg
// One wave = one 16-row x NC tile; no LDS, no barriers. AF32: A is f32 (layer 0,
// converted to fp16 in-register before MFMA).
template <int K, int NC, bool AF32>
__global__ __launch_bounds__(256) void gemm_mfma(const void* __restrict__ Av,
                                                 const __half* __restrict__ Wt,
                                                 __half* __restrict__ Out,
                                                 const float* __restrict__ dinv,
                                                 int N) {
  constexpr int NT = (NC + 15) / 16;     // col tiles: 4 (NC=64) or 3 (NC=40)
  int lane = threadIdx.x & 63;
  int r16 = lane & 15;
  int kq = lane >> 4;
  int wid = blockIdx.x * 4 + (threadIdx.x >> 6);
  int ntiles = (N + 15) >> 4;
  if (wid >= ntiles) return;
  int r0 = wid << 4;

  const __half* Ah = (const __half*)Av;
  const float* Af = (const float*)Av;
  int arow = r0 + r16;
  if (arow >= N) arow = N - 1;

  f32x4 acc[NT];
#pragma unroll
  for (int t2 = 0; t2 < NT; ++t2) acc[t2] = (f32x4){0.f, 0.f, 0.f, 0.f};

#pragma unroll
  for (int s = 0; s < K / 32; ++s) {
    half8 a;
    if constexpr (AF32) {
      const float* ap = Af + (size_t)arow * K + s * 32 + kq * 8;
      float4 v0 = *(const float4*)ap;
      float4 v1 = *(const float4*)(ap + 4);
      a[0] = (_Float16)v0.x; a[1] = (_Float16)v0.y;
      a[2] = (_Float16)v0.z; a[3] = (_Float16)v0.w;
      a[4] = (_Float16)v1.x; a[5] = (_Float16)v1.y;
      a[6] = (_Float16)v1.z; a[7] = (_Float16)v1.w;
    } else {
      a = *(const half8*)(Ah + (size_t)arow * K + s * 32 + kq * 8);
    }
#pragma unroll
    for (int t2 = 0; t2 < NT; ++t2) {
      half8 b = *(const half8*)(Wt + (size_t)(t2 * 16 + r16) * K + s * 32 + kq * 8);
      acc[t2] = __builtin_amdgcn_mfma_f32_16x16x32_f16(a, b, acc[t2], 0, 0, 0);
    }
  }

  // epilogue: rows r0 + 4*kq + b, col = t2*16 + r16
  float4 dv = *(const float4*)(dinv + r0 + kq * 4);
  float ds[4] = {dv.x, dv.y, dv.z, dv.w};
#pragma unroll
  for (int b = 0; b < 4; ++b) {
    int gr = r0 + kq * 4 + b;
#pragma unroll
    for (int t2 = 0; t2 < NT; ++t2) {
      int col = t2 * 16 + r16;
      if (col < NC) Out[(size_t)gr * NC + col] = __float2half_rn(ds[b] * acc[t2][b]);
    }
  }
}

// ---------------- sparse aggregation: one wave per node, fp16 gather ---------
// Row-major G: one edge = one 128B line request (line-rate optimal; round-7
// planar proved line-request count, not bytes, is the wall). 8 edge-slots x
// 8 feature-octs, f32 accumulate, 3-level shfl_xor fold.
template <int F, bool HOUT>
__global__ __launch_bounds__(256) void agg_kernel(const __half* __restrict__ G,
                                                  const int* __restrict__ row_ptr,
                                                  const int* __restrict__ ew,
                                                  const float* __restrict__ dinv,
                                                  void* __restrict__ HoutV, int N) {
  constexpr int FO = F / 8;
  int gid = blockIdx.x * blockDim.x + threadIdx.x;
  int v = gid >> 6;
  if (v >= N) return;
  int lane = threadIdx.x & 63;
  int eg = lane >> 3;
  int fo = lane & 7;
  bool fok = (fo < FO);
  int foc = fok ? fo : FO - 1;

  float acc[8];
#pragma unroll
  for (int i = 0; i < 8; ++i) acc[i] = 0.f;

#define GLD(s) (*(const uint4*)(G + (size_t)(s) * F + foc * 8))
  auto addrow = [&](uint4 q) {
    const __half2* h = (const __half2*)&q;
#pragma unroll
    for (int i = 0; i < 4; ++i) {
      float2 f = __half22float2(h[i]);
      acc[2 * i] += f.x;
      acc[2 * i + 1] += f.y;
    }
  };

  if (eg == 0) addrow(GLD(v));       // self-loop term

  int beg = __builtin_amdgcn_readfirstlane(row_ptr[v]);
  int end = __builtin_amdgcn_readfirstlane(row_ptr[v + 1]);
  int j = beg;
  for (; j + 16 <= end; j += 16) {
    int s0 = ew[j + eg];
    int s1 = ew[j + 8 + eg];
    uint4 a = GLD(s0);
    uint4 b = GLD(s1);
    addrow(a);
    addrow(b);
  }
  if (j + 8 <= end) {
    addrow(GLD(ew[j + eg]));
    j += 8;
  }
  {
    int idx = j + eg;
    if (idx < end) addrow(GLD(ew[idx]));
  }
#undef GLD

#pragma unroll
  for (int m = 8; m <= 32; m <<= 1) {
#pragma unroll
    for (int i = 0; i < 8; ++i) acc[i] += __shfl_xor(acc[i], m);
  }

  if (fok) {
    float dv = dinv[v];
    if constexpr (HOUT) {
      __half* Hout = (__half*)HoutV;
      union { __half2 h2[4]; uint4 u; } cv;
      cv.h2[0] = __floats2half2_rn(fmaxf(dv * acc[0], 0.f), fmaxf(dv * acc[1], 0.f));
      cv.h2[1] = __floats2half2_rn(fmaxf(dv * acc[2], 0.f), fmaxf(dv * acc[3], 0.f));
      cv.h2[2] = __floats2half2_rn(fmaxf(dv * acc[4], 0.f), fmaxf(dv * acc[5], 0.f));
      cv.h2[3] = __floats2half2_rn(fmaxf(dv * acc[6], 0.f), fmaxf(dv * acc[7], 0.f));
      *(uint4*)(Hout + (size_t)v * F + fo * 8) = cv.u;
    } else {
      float* Hout = (float*)HoutV;
      float4 o0, o1;
      o0.x = fmaxf(dv * acc[0], 0.f);
      o0.y = fmaxf(dv * acc[1], 0.f);
      o0.z = fmaxf(dv * acc[2], 0.f);
      o0.w = fmaxf(dv * acc[3], 0.f);
      o1.x = fmaxf(dv * acc[4], 0.f);
      o1.y = fmaxf(dv * acc[5], 0.f);
      o1.z = fmaxf(dv * acc[6], 0.f);
      o1.w = fmaxf(dv * acc[7], 0.f);
      float4* outp = (float4*)(Hout + (size_t)v * F + fo * 8);
      outp[0] = o0;
      outp[1] = o1;
    }
  }
}

extern "C" void kernel_launch(void* const* d_in, const int* in_sizes, int n_in,
                              void* d_out, int out_size, void* d_ws, size_t ws_size,
                              hipStream_t stream) {
  const float* x  = (const float*)d_in[0];
  const int*   eg = (const int*)d_in[1];
  const float* W0 = (const float*)d_in[2];
  const float* W1 = (const float*)d_in[3];
  const float* W2 = (const float*)d_in[4];
  float* out = (float*)d_out;

  const int N = in_sizes[0] / N_FEAT0;  // 100000
  const int E = in_sizes[1] / 2;        // 1600000
  const int* esrc = eg;
  const int* edst = eg + E;
  const int nbuck = (N + BSZ - 1) >> BSH;  // 196

  // workspace layout (256B aligned)
  char* p = (char*)d_ws;
  auto alloc = [&](size_t bytes) {
    char* r = p;
    p += (bytes + 255) & ~(size_t)255;
    return r;
  };
  int*    bfill   = (int*)alloc(256 * 4);
  int*    row_ptr = (int*)alloc((size_t)(N + 1) * 4);
  float*  dinv    = (float*)alloc((size_t)N * 4);
  int*    ew      = (int*)alloc((size_t)E * 4);
  __half* Wt0     = (__half*)alloc(8192 * 2);
  __half* Wt1     = (__half*)alloc(4096 * 2);
  __half* Wt2     = (__half*)alloc(3072 * 2);
  __half* bufG    = (__half*)alloc((size_t)N * HID * 2);   // 12.8 MB (G1, then G2)
  __half* bufH    = (__half*)alloc((size_t)N * HID * 2);   // 12.8 MB (H1, then H2)
  __half* bufG3   = (__half*)alloc((size_t)N * NCLS * 2);  // 8 MB
  // slab aliases bufH (9.63 MB <= 12.8 MB); build reads it before agg1 writes
  // bufH (stream-ordered).
  int* slab = (int*)bufH;

  hipMemsetAsync(bfill, 0, 256 * 4, stream);

  prep_w_kernel<<<60, 256, 0, stream>>>(W0, W1, W2, Wt0, Wt1, Wt2);
  const int sblocks = (E + STILE - 1) / STILE;  // 391
  scatter_kernel<<<sblocks, 256, 0, stream>>>(esrc, edst, bfill, slab, E);
  build_kernel<<<nbuck, 512, 0, stream>>>(slab, bfill, row_ptr, dinv, ew, N, nbuck);

  const int ntiles = (N + 15) / 16;             // 6250
  const int mblocks = (ntiles + 3) / 4;         // 1563
  const int ablocks = (N + 3) / 4;
  // layer 0: 128 -> 64 (f32 x, in-register fp16 cvt, MFMA)
  gemm_mfma<128, 64, true><<<mblocks, 256, 0, stream>>>(x, Wt0, bufG, dinv, N);
  agg_kernel<64, true><<<ablocks, 256, 0, stream>>>(bufG, row_ptr, ew, dinv, bufH, N);
  // layer 1: 64 -> 64 (fp16, MFMA)
  gemm_mfma<64, 64, false><<<mblocks, 256, 0, stream>>>(bufH, Wt1, bufG, dinv, N);
  agg_kernel<64, true><<<ablocks, 256, 0, stream>>>(bufG, row_ptr, ew, dinv, bufH, N);
  // layer 2: 64 -> 40 (fp16, MFMA, Wt2 zero-padded to 48 cols)
  gemm_mfma<64, 40, false><<<mblocks, 256, 0, stream>>>(bufH, Wt2, bufG3, dinv, N);
  agg_kernel<40, false><<<ablocks, 256, 0, stream>>>(bufG3, row_ptr, ew, dinv, out, N);
}